// Round 12
// baseline (460.789 us; speedup 1.0000x reference)
//
#include <hip/hip_runtime.h>

#define TT 100
#define DD 100
#define DC 25      // DD/4
#define PP 10
#define BBATCH 256
#define OC 80
#define NWD 8      // waves per dir (16 waves/block total)
#define NR 2       // rows per wave per group (register tile; R6-proven)

typedef float v2f __attribute__((ext_vector_type(2)));
typedef float v4f __attribute__((ext_vector_type(4)));

static constexpr float FEPS = 1e-6f;

__device__ __forceinline__ int   f2i(float x) { return __builtin_bit_cast(int, x); }
__device__ __forceinline__ float i2f(int x)   { return __builtin_bit_cast(float, x); }

// DPP row_ror:n within 16-lane rows — VALU pipe, no LDS traffic.
#define ROR_F(v, ctrl) i2f(__builtin_amdgcn_update_dpp(0, f2i(v), (ctrl), 0xf, 0xf, false))
#define ROR_I(v, ctrl) __builtin_amdgcn_update_dpp(0, (v), (ctrl), 0xf, 0xf, false)

__device__ __forceinline__ v2f xswap32_f(float v) {
#if __has_builtin(__builtin_amdgcn_permlane32_swap)
  auto pr = __builtin_amdgcn_permlane32_swap((unsigned)f2i(v), (unsigned)f2i(v), false, false);
  v2f r; r.x = i2f((int)pr[0]); r.y = i2f((int)pr[1]);
  return r;
#else
  v2f r; r.x = v; r.y = __shfl_xor(v, 32, 64);
  return r;
#endif
}

__device__ __forceinline__ float wave_sum(float v) {
  v += ROR_F(v, 0x121);
  v += ROR_F(v, 0x122);
  v += ROR_F(v, 0x124);
  v += ROR_F(v, 0x128);
  v += i2f(__builtin_amdgcn_ds_swizzle(f2i(v), 0x401f));   // lane ^ 16
  v2f s = xswap32_f(v);                                    // lane ^ 32
  return s.x + s.y;
}

__device__ __forceinline__ float wave_max(float v) {
  v = fmaxf(v, ROR_F(v, 0x121));
  v = fmaxf(v, ROR_F(v, 0x122));
  v = fmaxf(v, ROR_F(v, 0x124));
  v = fmaxf(v, ROR_F(v, 0x128));
  v = fmaxf(v, i2f(__builtin_amdgcn_ds_swizzle(f2i(v), 0x401f)));
  v2f s = xswap32_f(v);
  return fmaxf(s.x, s.y);
}

__device__ __forceinline__ void amax2(float& v, int& i, float ov, int oi) {
  if (ov > v || (ov == v && oi < i)) { v = ov; i = oi; }
}

__device__ __forceinline__ void wave_argmax(float& v, int& idx) {
  amax2(v, idx, ROR_F(v, 0x121), ROR_I(idx, 0x121));
  amax2(v, idx, ROR_F(v, 0x122), ROR_I(idx, 0x122));
  amax2(v, idx, ROR_F(v, 0x124), ROR_I(idx, 0x124));
  amax2(v, idx, ROR_F(v, 0x128), ROR_I(idx, 0x128));
  amax2(v, idx, i2f(__builtin_amdgcn_ds_swizzle(f2i(v), 0x401f)),
        __builtin_amdgcn_ds_swizzle(idx, 0x401f));
#if __has_builtin(__builtin_amdgcn_permlane32_swap)
  {
    auto rv = __builtin_amdgcn_permlane32_swap((unsigned)f2i(v), (unsigned)f2i(v), false, false);
    auto ri = __builtin_amdgcn_permlane32_swap((unsigned)idx, (unsigned)idx, false, false);
    amax2(v, idx, i2f((int)rv[0]), (int)ri[0]);
    amax2(v, idx, i2f((int)rv[1]), (int)ri[1]);
  }
#else
  amax2(v, idx, __shfl_xor(v, 32, 64), __shfl_xor(idx, 32, 64));
#endif
}

// FUSED-DIR BLOCK (R10-proven residency): 1024 threads = 16 waves (0-7: dir 0;
// 8-15: dir 1), grid 256 = one block/CU => 16 waves/CU guaranteed (41% occ).
// LAUNCH-BOUNDS SEMANTICS (measured R1/R3/R9/R10/R11): VGPR cap =
// 512 / (arg2 * waves_per_block_per_SIMD) — arg2 acts as min WORKGROUPS/CU:
//   (512,2)->128, (512,3)->85, (512,4)->64, (1024,2)->64 [R11: still spilled].
// => (1024,1): 1 * 4 waves/SIMD -> cap 512/4 = 128. R6 body needs ~116. This
// is the first config that actually combines no-spill with 16 waves/CU.
__global__ __launch_bounds__(1024, 1) void match_kernel(
    const float* __restrict__ s1, const float* __restrict__ s2,
    const float* __restrict__ w1, const float* __restrict__ w2,
    const float* __restrict__ w3, const float* __restrict__ w4,
    const float* __restrict__ w5, const float* __restrict__ w6,
    const float* __restrict__ w7, const float* __restrict__ w8,
    float* __restrict__ out)
{
  const int b    = blockIdx.x;
  const int tid  = threadIdx.x;
  const int lane = tid & 63;
  const int wv   = tid >> 6;        // 0..15
  const int dird = wv >> 3;         // 0 or 1 (per-wave dir)
  const int wvd  = wv & 7;          // wave index within dir
  const int doff = dird * DD;

  const float* wfull = dird ? w2 : w1;
  const float* wmax  = dird ? w4 : w3;
  const float* wmean = dird ? w6 : w5;
  const float* watt2 = dird ? w8 : w7;   // fwd: max-att (w7); bwd: mean-att (w8)

  // s2 in d-chunked layout per dir: d = 4c+k. j-stride = 16B (b128-able,
  // conflict-free lane-over-j); chunk stride 404 dwords == 20 mod 32.
  __shared__ __align__(16) float S2V[2][DC][TT + 1][4];
  __shared__ __align__(16) float W2SQ[2][PP][DD];     // p-row layout: norm passes
  __shared__ __align__(16) float W2T[2][DC][4][PP];   // d-major: Phase-B v2f p-pairs
  __shared__ float N2PI[2][TT];
  __shared__ float N2WI[2][TT][11];     // padded: (11j+p)%32 -> 2-way free
  // Wave-private regions (wave wv owns rows [wv*NR, wv*NR+NR)): no barriers.
  __shared__ __align__(16) float S1R[16 * NR][DD];
  __shared__ __align__(16) float CROW[16 * NR][DD];
  __shared__ float N1PI[16 * NR];
  __shared__ float N1WI[16 * NR][PP];
  __shared__ int   ARGJ[16 * NR];

  // ---- Phase 1: load s2 tiles (both dirs, d-chunked) + maxpool w^2 ----
  for (int idx = tid; idx < 2 * TT * DD; idx += 1024) {
    int dd  = idx / (TT * DD);
    int rem = idx - dd * (TT * DD);
    int j = rem / DD, d = rem - j * DD;
    S2V[dd][d >> 2][j][d & 3] = s2[(j * BBATCH + b) * (2 * DD) + dd * DD + d];
  }
  for (int idx = tid; idx < 2 * PP * DD; idx += 1024) {
    int dd  = idx / (PP * DD);
    int rem = idx - dd * (PP * DD);
    int p = rem / DD, d = rem - p * DD;
    const float* wm = dd ? w4 : w3;
    float v = wm[p * DD + d];
    float v2 = v * v;
    W2SQ[dd][p][d] = v2;
    W2T[dd][d >> 2][d & 3][p] = v2;
  }
  __syncthreads();

  // ---- Phase 2: s2 norms (plain + weighted rsqrt), both dirs ----
  const int TPD = TT + TT * PP;   // 1100 tasks per dir
  for (int task = tid; task < 2 * TPD; task += 1024) {
    int dd = task / TPD;
    int t  = task - dd * TPD;
    if (t < TT) {
      int j = t;
      float a = 0.f;
      for (int c = 0; c < DC; ++c) {
        v4f f = *(const v4f*)&S2V[dd][c][j][0];
#pragma unroll
        for (int k = 0; k < 4; ++k) a = fmaf(f[k], f[k], a);
      }
      N2PI[dd][j] = 1.0f / sqrtf(fmaxf(a, FEPS));   // argmax-sensitive cos
    } else {
      int q = t - TT; int j = q / PP, p = q - j * PP;
      float a = 0.f;
      for (int c = 0; c < DC; ++c) {
        v4f f = *(const v4f*)&S2V[dd][c][j][0];
        v4f w = *(const v4f*)&W2SQ[dd][p][4 * c];
#pragma unroll
        for (int k = 0; k < 4; ++k) a = fmaf(f[k] * f[k], w[k], a);
      }
      N2WI[dd][j][p] = rsqrtf(fmaxf(a, FEPS));
    }
  }
  __syncthreads();
  // ---- After this point: ZERO barriers. Remaining LDS state is read-only
  // (S2V/W2SQ/W2T/N2*) or wave-private (S1R/CROW/N1*/ARGJ).

  const int  j0   = lane;
  const int  j1   = 64 + lane;
  const bool act1 = (j1 < TT);
  const int  j1c  = act1 ? j1 : (TT - 1);
  const bool actd = (64 + lane) < DD;
  const int  d1   = actd ? (64 + lane) : (DD - 1);
  const int  c0i  = lane >> 2, k0 = lane & 3;      // phase-D d0 = lane
  const int  c1i  = d1 >> 2,   k1 = d1 & 3;        // phase-D d1

  const int sl = wv * NR;

  // ---- 50 row-groups (2 rows) per dir, strided over this dir's 8 waves ----
  for (int g = wvd; g < 50; g += NWD) {
    const int i0 = g * NR;         // rows i0..i0+1, always < 100

    // wave-private S1R staging: 2 rows x 25 float4 chunks = 50 tasks
    if (lane < NR * DC) {
      int rr = lane / DC, c = lane - rr * DC;
      *(v4f*)&S1R[sl + rr][4 * c] =
          *(const v4f*)&s1[((i0 + rr) * BBATCH + b) * (2 * DD) + doff + 4 * c];
    }

    // wave-private s1 norms: 2 rows x (1 plain + 10 weighted) = 22 lane-tasks
    if (lane < NR * 11) {
      int rr = lane / 11, q = lane - rr * 11;
      if (q == 0) {
        float a = 0.f;
        for (int c = 0; c < DC; ++c) {
          v4f f = *(const v4f*)&S1R[sl + rr][4 * c];
#pragma unroll
          for (int k = 0; k < 4; ++k) a = fmaf(f[k], f[k], a);
        }
        N1PI[sl + rr] = 1.0f / sqrtf(fmaxf(a, FEPS));
      } else {
        int p = q - 1;
        float a = 0.f;
        for (int c = 0; c < DC; ++c) {
          v4f f = *(const v4f*)&S1R[sl + rr][4 * c];
          v4f w = *(const v4f*)&W2SQ[dird][p][4 * c];
#pragma unroll
          for (int k = 0; k < 4; ++k) a = fmaf(f[k] * f[k], w[k], a);
        }
        N1WI[sl + rr][p] = rsqrtf(fmaxf(a, FEPS));
      }
    }

    float rs[NR] = {0, 0};
    v2f attp[NR] = {{0, 0}, {0, 0}};

    // ---- Phase B: scalar dot (j0,j1); maxpool FMAs packed over p-pairs ----
    // (accumulation order per (j,p) accumulator identical to R6 -> bit-exact)
    float dot0[NR] = {0, 0};
    float dot1[NR] = {0, 0};
    v2f wap[NR][2][5];                  // [row][j0/j1][p-pair] = 40 VGPRs
#pragma unroll
    for (int r = 0; r < NR; ++r)
#pragma unroll
      for (int pp = 0; pp < 5; ++pp) {
        wap[r][0][pp] = (v2f){0.f, 0.f};
        wap[r][1][pp] = (v2f){0.f, 0.f};
      }

    for (int c = 0; c < DC; ++c) {
      v4f s2a4 = *(const v4f*)&S2V[dird][c][j0][0];
      v4f s2b4 = *(const v4f*)&S2V[dird][c][j1c][0];
      v4f s1v[NR];
#pragma unroll
      for (int r = 0; r < NR; ++r) s1v[r] = *(const v4f*)&S1R[sl + r][4 * c];
#pragma unroll
      for (int k = 0; k < 4; ++k) {
        v4f wA = *(const v4f*)&W2T[dird][c][k][0];   // p0..3
        v4f wB = *(const v4f*)&W2T[dird][c][k][4];   // p4..7
        v2f wp4 = *(const v2f*)&W2T[dird][c][k][8];  // p8..9
        v2f wp0 = __builtin_shufflevector(wA, wA, 0, 1);
        v2f wp1 = __builtin_shufflevector(wA, wA, 2, 3);
        v2f wp2 = __builtin_shufflevector(wB, wB, 0, 1);
        v2f wp3 = __builtin_shufflevector(wB, wB, 2, 3);
#pragma unroll
        for (int r = 0; r < NR; ++r) {
          float ta0 = s1v[r][k] * s2a4[k];
          float ta1 = s1v[r][k] * s2b4[k];
          dot0[r] += ta0;
          dot1[r] += ta1;
          v2f t0; t0.x = ta0; t0.y = ta0;
          v2f t1; t1.x = ta1; t1.y = ta1;
          wap[r][0][0] = __builtin_elementwise_fma(t0, wp0, wap[r][0][0]);
          wap[r][0][1] = __builtin_elementwise_fma(t0, wp1, wap[r][0][1]);
          wap[r][0][2] = __builtin_elementwise_fma(t0, wp2, wap[r][0][2]);
          wap[r][0][3] = __builtin_elementwise_fma(t0, wp3, wap[r][0][3]);
          wap[r][0][4] = __builtin_elementwise_fma(t0, wp4, wap[r][0][4]);
          wap[r][1][0] = __builtin_elementwise_fma(t1, wp0, wap[r][1][0]);
          wap[r][1][1] = __builtin_elementwise_fma(t1, wp1, wap[r][1][1]);
          wap[r][1][2] = __builtin_elementwise_fma(t1, wp2, wap[r][1][2]);
          wap[r][1][3] = __builtin_elementwise_fma(t1, wp3, wap[r][1][3]);
          wap[r][1][4] = __builtin_elementwise_fma(t1, wp4, wap[r][1][4]);
        }
      }
    }

    // ---- Phase C: cos rows, rowsum, argmax, maxpool (DPP/permlane reductions) ----
#pragma unroll
    for (int r = 0; r < NR; ++r) {
      float n1pi_r = N1PI[sl + r];
      float c0 = dot0[r] * (n1pi_r * N2PI[dird][j0]);
      float c1 = dot1[r] * (n1pi_r * N2PI[dird][j1c]);
      CROW[sl + r][j0] = c0;
      if (act1) CROW[sl + r][j1] = c1;
      rs[r] = wave_sum(c0 + (act1 ? c1 : 0.f));

      float mv = c0; int mi = j0;
      if (act1 && (c1 > mv)) { mv = c1; mi = j1; }
      wave_argmax(mv, mi);
      if (lane == 0) ARGJ[sl + r] = mi;

#pragma unroll
      for (int p = 0; p < PP; ++p) {
        float a0 = (p & 1) ? wap[r][0][p >> 1].y : wap[r][0][p >> 1].x;
        float a1 = (p & 1) ? wap[r][1][p >> 1].y : wap[r][1][p >> 1].x;
        float v0 = a0 * N2WI[dird][j0][p];
        float v1 = act1 ? a1 * N2WI[dird][j1c][p] : -3.4e38f;
        float m = wave_max(fmaxf(v0, v1));
        if (lane == 0) {
          out[((i0 + r) * BBATCH + b) * OC + 20 + dird * PP + p] = m * N1WI[sl + r][p];
        }
      }
    }

    // ---- Phase D: mean-att accumulation, packed (d0,d1); reads own CROW rows ----
    for (int j = 0; j < TT; ++j) {
      v2f s2ab; s2ab.x = S2V[dird][c0i][j][k0]; s2ab.y = S2V[dird][c1i][j][k1];
#pragma unroll
      for (int r = 0; r < NR; ++r) {
        float cv = CROW[sl + r][j];
        v2f cc; cc.x = cv; cc.y = cv;
        attp[r] = __builtin_elementwise_fma(cc, s2ab, attp[r]);
      }
    }

    // overwrite own CROW rows with att rows (same-wave ordering suffices)
#pragma unroll
    for (int r = 0; r < NR; ++r) {
      float inv = 1.0f / (rs[r] + FEPS);
      CROW[sl + r][lane] = attp[r].x * inv;
      if (actd) CROW[sl + r][64 + lane] = attp[r].y * inv;
    }

    // ---- Phase E: epilogue: 60 tasks = 2 rows x {full, mean-att, att2} x 10 p
    if (lane < NR * 30) {
      int tk = lane;
      int r = tk / 30;
      int q = tk - r * 30;
      int set = q / PP;
      int p = q - set * PP;
      const float* wrow = (set == 0 ? wfull : (set == 1 ? wmean : watt2)) + p * DD;
      // reference quirk: s2.reshape(-1,D)[argmax] == s2f[0, argmax, :] (fwd only)
      const float* gat = s2 + ARGJ[sl + r] * (2 * DD);
      float num = 0.f, nx = 0.f, ny = 0.f;
      for (int c = 0; c < DC; ++c) {
        v4f x4 = *(const v4f*)&S1R[sl + r][4 * c];
        v4f y4;
        if (set == 0)                     y4 = *(const v4f*)&S2V[dird][c][TT - 1][0];
        else if (set == 1 || dird == 1)   y4 = *(const v4f*)&CROW[sl + r][4 * c];
        else                              y4 = *(const v4f*)&gat[4 * c];
        v4f w4 = *(const v4f*)&wrow[4 * c];
#pragma unroll
        for (int k = 0; k < 4; ++k) {
          float w2v = w4[k] * w4[k];
          num = fmaf(x4[k] * y4[k], w2v, num);
          nx  = fmaf(x4[k] * x4[k], w2v, nx);
          ny  = fmaf(y4[k] * y4[k], w2v, ny);
        }
      }
      float cres = num * rsqrtf(fmaxf(nx, FEPS)) * rsqrtf(fmaxf(ny, FEPS));
      int ch = (set == 0 ? 0 : (set == 1 ? 40 : 60)) + dird * PP + p;
      out[((i0 + r) * BBATCH + b) * OC + ch] = cres;
    }
  }
}

extern "C" void kernel_launch(void* const* d_in, const int* in_sizes, int n_in,
                              void* d_out, int out_size, void* d_ws, size_t ws_size,
                              hipStream_t stream) {
  const float* s1 = (const float*)d_in[0];
  const float* s2 = (const float*)d_in[1];
  match_kernel<<<dim3(BBATCH), dim3(1024), 0, stream>>>(
      s1, s2,
      (const float*)d_in[2], (const float*)d_in[3],
      (const float*)d_in[4], (const float*)d_in[5],
      (const float*)d_in[6], (const float*)d_in[7],
      (const float*)d_in[8], (const float*)d_in[9],
      (float*)d_out);
}

// Round 13
// 441.356 us; speedup vs baseline: 1.0440x; 1.0440x over previous
//
#include <hip/hip_runtime.h>

#define TT 100
#define DD 100
#define DC 25      // DD/4
#define PP 10
#define BBATCH 256
#define OC 80
#define NWD 8      // waves per dir (16 waves/block total)
#define NR 2       // rows per wave per group (register tile; R6-proven)

typedef float v2f __attribute__((ext_vector_type(2)));
typedef float v4f __attribute__((ext_vector_type(4)));

static constexpr float FEPS = 1e-6f;

__device__ __forceinline__ int   f2i(float x) { return __builtin_bit_cast(int, x); }
__device__ __forceinline__ float i2f(int x)   { return __builtin_bit_cast(float, x); }

// DPP row_ror:n within 16-lane rows — VALU pipe, no LDS traffic.
#define ROR_F(v, ctrl) i2f(__builtin_amdgcn_update_dpp(0, f2i(v), (ctrl), 0xf, 0xf, false))
#define ROR_I(v, ctrl) __builtin_amdgcn_update_dpp(0, (v), (ctrl), 0xf, 0xf, false)

__device__ __forceinline__ v2f xswap32_f(float v) {
#if __has_builtin(__builtin_amdgcn_permlane32_swap)
  auto pr = __builtin_amdgcn_permlane32_swap((unsigned)f2i(v), (unsigned)f2i(v), false, false);
  v2f r; r.x = i2f((int)pr[0]); r.y = i2f((int)pr[1]);
  return r;
#else
  v2f r; r.x = v; r.y = __shfl_xor(v, 32, 64);
  return r;
#endif
}

__device__ __forceinline__ float wave_sum(float v) {
  v += ROR_F(v, 0x121);
  v += ROR_F(v, 0x122);
  v += ROR_F(v, 0x124);
  v += ROR_F(v, 0x128);
  v += i2f(__builtin_amdgcn_ds_swizzle(f2i(v), 0x401f));   // lane ^ 16
  v2f s = xswap32_f(v);                                    // lane ^ 32
  return s.x + s.y;
}

__device__ __forceinline__ float wave_max(float v) {
  v = fmaxf(v, ROR_F(v, 0x121));
  v = fmaxf(v, ROR_F(v, 0x122));
  v = fmaxf(v, ROR_F(v, 0x124));
  v = fmaxf(v, ROR_F(v, 0x128));
  v = fmaxf(v, i2f(__builtin_amdgcn_ds_swizzle(f2i(v), 0x401f)));
  v2f s = xswap32_f(v);
  return fmaxf(s.x, s.y);
}

__device__ __forceinline__ void amax2(float& v, int& i, float ov, int oi) {
  if (ov > v || (ov == v && oi < i)) { v = ov; i = oi; }
}

__device__ __forceinline__ void wave_argmax(float& v, int& idx) {
  amax2(v, idx, ROR_F(v, 0x121), ROR_I(idx, 0x121));
  amax2(v, idx, ROR_F(v, 0x122), ROR_I(idx, 0x122));
  amax2(v, idx, ROR_F(v, 0x124), ROR_I(idx, 0x124));
  amax2(v, idx, ROR_F(v, 0x128), ROR_I(idx, 0x128));
  amax2(v, idx, i2f(__builtin_amdgcn_ds_swizzle(f2i(v), 0x401f)),
        __builtin_amdgcn_ds_swizzle(idx, 0x401f));
#if __has_builtin(__builtin_amdgcn_permlane32_swap)
  {
    auto rv = __builtin_amdgcn_permlane32_swap((unsigned)f2i(v), (unsigned)f2i(v), false, false);
    auto ri = __builtin_amdgcn_permlane32_swap((unsigned)idx, (unsigned)idx, false, false);
    amax2(v, idx, i2f((int)rv[0]), (int)ri[0]);
    amax2(v, idx, i2f((int)rv[1]), (int)ri[1]);
  }
#else
  amax2(v, idx, __shfl_xor(v, 32, 64), __shfl_xor(idx, 32, 64));
#endif
}

// VGPR BUDGET MODEL (fits all R0-R12 data): usable arch-VGPR budget = 256 per
// SIMD-resident wave set => cap = 256 / (mandatory waves/SIMD).
//   512-thr blocks: (512,2)->128, (512,3)->85, (512,4)->64 (all measured).
//   1024-thr blocks: 16 waves MUST co-reside -> 4 waves/SIMD -> cap 64,
//   REGARDLESS of launch_bounds arg2 (R10/R11/R12 all measured 64).
// Occupancy: floor(256/VGPR) waves/SIMD (R6: 116->2/SIMD=20%; R1: 64->4/SIMD=44%).
// => 16 waves/CU requires the kernel to GENUINELY FIT 64 VGPR.
// This round: Phase B split into two p-passes (pairs 0-2 then 3-4), each
// consumed into outputs before the next starts. Worst-point live set ~58 <= 64.
// Per-accumulator FMA order unchanged -> bit-exact vs R6/R10/R12.
__global__ __launch_bounds__(1024, 1) void match_kernel(
    const float* __restrict__ s1, const float* __restrict__ s2,
    const float* __restrict__ w1, const float* __restrict__ w2,
    const float* __restrict__ w3, const float* __restrict__ w4,
    const float* __restrict__ w5, const float* __restrict__ w6,
    const float* __restrict__ w7, const float* __restrict__ w8,
    float* __restrict__ out)
{
  const int b    = blockIdx.x;
  const int tid  = threadIdx.x;
  const int lane = tid & 63;
  const int wv   = tid >> 6;        // 0..15
  const int dird = wv >> 3;         // 0 or 1 (per-wave dir)
  const int wvd  = wv & 7;          // wave index within dir
  const int doff = dird * DD;

  const float* wfull = dird ? w2 : w1;
  const float* wmean = dird ? w6 : w5;
  const float* watt2 = dird ? w8 : w7;   // fwd: max-att (w7); bwd: mean-att (w8)

  // s2 in d-chunked layout per dir: d = 4c+k. j-stride = 16B (b128-able,
  // conflict-free lane-over-j); chunk stride 404 dwords == 20 mod 32.
  __shared__ __align__(16) float S2V[2][DC][TT + 1][4];
  __shared__ __align__(16) float W2SQ[2][PP][DD];     // p-row layout: norm passes
  __shared__ __align__(16) float W2T[2][DC][4][PP];   // d-major: Phase-B v2f p-pairs
  __shared__ float N2PI[2][TT];
  __shared__ float N2WI[2][TT][11];     // padded: (11j+p)%32 -> 2-way free
  // Wave-private regions (wave wv owns rows [wv*NR, wv*NR+NR)): no barriers.
  __shared__ __align__(16) float S1R[16 * NR][DD];
  __shared__ __align__(16) float CROW[16 * NR][DD];
  __shared__ float N1PI[16 * NR];
  __shared__ float N1WI[16 * NR][PP];
  __shared__ int   ARGJ[16 * NR];

  // ---- Phase 1: load s2 tiles (both dirs, d-chunked) + maxpool w^2 ----
  for (int idx = tid; idx < 2 * TT * DD; idx += 1024) {
    int dd  = idx / (TT * DD);
    int rem = idx - dd * (TT * DD);
    int j = rem / DD, d = rem - j * DD;
    S2V[dd][d >> 2][j][d & 3] = s2[(j * BBATCH + b) * (2 * DD) + dd * DD + d];
  }
  for (int idx = tid; idx < 2 * PP * DD; idx += 1024) {
    int dd  = idx / (PP * DD);
    int rem = idx - dd * (PP * DD);
    int p = rem / DD, d = rem - p * DD;
    const float* wm = dd ? w4 : w3;
    float v = wm[p * DD + d];
    float v2 = v * v;
    W2SQ[dd][p][d] = v2;
    W2T[dd][d >> 2][d & 3][p] = v2;
  }
  __syncthreads();

  // ---- Phase 2: s2 norms (plain + weighted rsqrt), both dirs ----
  const int TPD = TT + TT * PP;   // 1100 tasks per dir
  for (int task = tid; task < 2 * TPD; task += 1024) {
    int dd = task / TPD;
    int t  = task - dd * TPD;
    if (t < TT) {
      int j = t;
      float a = 0.f;
      for (int c = 0; c < DC; ++c) {
        v4f f = *(const v4f*)&S2V[dd][c][j][0];
#pragma unroll
        for (int k = 0; k < 4; ++k) a = fmaf(f[k], f[k], a);
      }
      N2PI[dd][j] = 1.0f / sqrtf(fmaxf(a, FEPS));   // argmax-sensitive cos
    } else {
      int q = t - TT; int j = q / PP, p = q - j * PP;
      float a = 0.f;
      for (int c = 0; c < DC; ++c) {
        v4f f = *(const v4f*)&S2V[dd][c][j][0];
        v4f w = *(const v4f*)&W2SQ[dd][p][4 * c];
#pragma unroll
        for (int k = 0; k < 4; ++k) a = fmaf(f[k] * f[k], w[k], a);
      }
      N2WI[dd][j][p] = rsqrtf(fmaxf(a, FEPS));
    }
  }
  __syncthreads();
  // ---- After this point: ZERO barriers. Remaining LDS state is read-only
  // (S2V/W2SQ/W2T/N2*) or wave-private (S1R/CROW/N1*/ARGJ).

  const int  j0   = lane;
  const int  j1   = 64 + lane;
  const bool act1 = (j1 < TT);
  const int  j1c  = act1 ? j1 : (TT - 1);
  const bool actd = (64 + lane) < DD;
  const int  d1   = actd ? (64 + lane) : (DD - 1);
  const int  c0i  = lane >> 2, k0 = lane & 3;      // phase-D d0 = lane
  const int  c1i  = d1 >> 2,   k1 = d1 & 3;        // phase-D d1

  const int sl = wv * NR;

  // ---- 50 row-groups (2 rows) per dir, strided over this dir's 8 waves ----
  for (int g = wvd; g < 50; g += NWD) {
    const int i0 = g * NR;         // rows i0..i0+1, always < 100

    // wave-private S1R staging: 2 rows x 25 float4 chunks = 50 tasks
    if (lane < NR * DC) {
      int rr = lane / DC, c = lane - rr * DC;
      *(v4f*)&S1R[sl + rr][4 * c] =
          *(const v4f*)&s1[((i0 + rr) * BBATCH + b) * (2 * DD) + doff + 4 * c];
    }

    // wave-private s1 norms: 2 rows x (1 plain + 10 weighted) = 22 lane-tasks
    if (lane < NR * 11) {
      int rr = lane / 11, q = lane - rr * 11;
      if (q == 0) {
        float a = 0.f;
        for (int c = 0; c < DC; ++c) {
          v4f f = *(const v4f*)&S1R[sl + rr][4 * c];
#pragma unroll
          for (int k = 0; k < 4; ++k) a = fmaf(f[k], f[k], a);
        }
        N1PI[sl + rr] = 1.0f / sqrtf(fmaxf(a, FEPS));
      } else {
        int p = q - 1;
        float a = 0.f;
        for (int c = 0; c < DC; ++c) {
          v4f f = *(const v4f*)&S1R[sl + rr][4 * c];
          v4f w = *(const v4f*)&W2SQ[dird][p][4 * c];
#pragma unroll
          for (int k = 0; k < 4; ++k) a = fmaf(f[k] * f[k], w[k], a);
        }
        N1WI[sl + rr][p] = rsqrtf(fmaxf(a, FEPS));
      }
    }

    float rs[NR];
    v2f attp[NR] = {{0, 0}, {0, 0}};

    // ================= Phase B/C — PASS A: dots + p-pairs 0..2 =============
    // Live set: wapA 24 + dot 4 + s1v 8 + s2 8 + w 6 + addr ~10 = ~60 <= 64.
    {
      float dot0[NR] = {0, 0};
      float dot1[NR] = {0, 0};
      v2f wapA[NR][2][3];               // [row][j0/j1][pair 0..2] = 24 VGPRs
#pragma unroll
      for (int r = 0; r < NR; ++r)
#pragma unroll
        for (int pp = 0; pp < 3; ++pp) {
          wapA[r][0][pp] = (v2f){0.f, 0.f};
          wapA[r][1][pp] = (v2f){0.f, 0.f};
        }

      for (int c = 0; c < DC; ++c) {
        v4f s2a4 = *(const v4f*)&S2V[dird][c][j0][0];
        v4f s2b4 = *(const v4f*)&S2V[dird][c][j1c][0];
        v4f s1v[NR];
#pragma unroll
        for (int r = 0; r < NR; ++r) s1v[r] = *(const v4f*)&S1R[sl + r][4 * c];
#pragma unroll
        for (int k = 0; k < 4; ++k) {
          v4f wA = *(const v4f*)&W2T[dird][c][k][0];   // p0..3
          v2f wp0 = __builtin_shufflevector(wA, wA, 0, 1);
          v2f wp1 = __builtin_shufflevector(wA, wA, 2, 3);
          v2f wp2 = *(const v2f*)&W2T[dird][c][k][4];  // p4..5
#pragma unroll
          for (int r = 0; r < NR; ++r) {
            float ta0 = s1v[r][k] * s2a4[k];
            float ta1 = s1v[r][k] * s2b4[k];
            dot0[r] += ta0;
            dot1[r] += ta1;
            v2f t0; t0.x = ta0; t0.y = ta0;
            v2f t1; t1.x = ta1; t1.y = ta1;
            wapA[r][0][0] = __builtin_elementwise_fma(t0, wp0, wapA[r][0][0]);
            wapA[r][0][1] = __builtin_elementwise_fma(t0, wp1, wapA[r][0][1]);
            wapA[r][0][2] = __builtin_elementwise_fma(t0, wp2, wapA[r][0][2]);
            wapA[r][1][0] = __builtin_elementwise_fma(t1, wp0, wapA[r][1][0]);
            wapA[r][1][1] = __builtin_elementwise_fma(t1, wp1, wapA[r][1][1]);
            wapA[r][1][2] = __builtin_elementwise_fma(t1, wp2, wapA[r][1][2]);
          }
        }
      }

      // ---- consume pass A: cos rows, rowsum, argmax, maxpool p0..5 ----
#pragma unroll
      for (int r = 0; r < NR; ++r) {
        float n1pi_r = N1PI[sl + r];
        float c0 = dot0[r] * (n1pi_r * N2PI[dird][j0]);
        float c1 = dot1[r] * (n1pi_r * N2PI[dird][j1c]);
        CROW[sl + r][j0] = c0;
        if (act1) CROW[sl + r][j1] = c1;
        rs[r] = wave_sum(c0 + (act1 ? c1 : 0.f));

        float mv = c0; int mi = j0;
        if (act1 && (c1 > mv)) { mv = c1; mi = j1; }
        wave_argmax(mv, mi);
        if (lane == 0) ARGJ[sl + r] = mi;

#pragma unroll
        for (int p = 0; p < 6; ++p) {
          float a0 = (p & 1) ? wapA[r][0][p >> 1].y : wapA[r][0][p >> 1].x;
          float a1 = (p & 1) ? wapA[r][1][p >> 1].y : wapA[r][1][p >> 1].x;
          float v0 = a0 * N2WI[dird][j0][p];
          float v1 = act1 ? a1 * N2WI[dird][j1c][p] : -3.4e38f;
          float m = wave_max(fmaxf(v0, v1));
          if (lane == 0) {
            out[((i0 + r) * BBATCH + b) * OC + 20 + dird * PP + p] = m * N1WI[sl + r][p];
          }
        }
      }
    } // wapA + dots dead here

    // ================= Phase B/C — PASS B: p-pairs 3..4 ====================
    // Live set: wapB 16 + s1v 8 + s2 8 + w 4 + addr ~10 = ~46.
    {
      v2f wapB[NR][2][2];               // [row][j0/j1][pair 3..4] = 16 VGPRs
#pragma unroll
      for (int r = 0; r < NR; ++r)
#pragma unroll
        for (int pp = 0; pp < 2; ++pp) {
          wapB[r][0][pp] = (v2f){0.f, 0.f};
          wapB[r][1][pp] = (v2f){0.f, 0.f};
        }

      for (int c = 0; c < DC; ++c) {
        v4f s2a4 = *(const v4f*)&S2V[dird][c][j0][0];
        v4f s2b4 = *(const v4f*)&S2V[dird][c][j1c][0];
        v4f s1v[NR];
#pragma unroll
        for (int r = 0; r < NR; ++r) s1v[r] = *(const v4f*)&S1R[sl + r][4 * c];
#pragma unroll
        for (int k = 0; k < 4; ++k) {
          v2f wp3 = *(const v2f*)&W2T[dird][c][k][6];  // p6..7
          v2f wp4 = *(const v2f*)&W2T[dird][c][k][8];  // p8..9
#pragma unroll
          for (int r = 0; r < NR; ++r) {
            float ta0 = s1v[r][k] * s2a4[k];
            float ta1 = s1v[r][k] * s2b4[k];
            v2f t0; t0.x = ta0; t0.y = ta0;
            v2f t1; t1.x = ta1; t1.y = ta1;
            wapB[r][0][0] = __builtin_elementwise_fma(t0, wp3, wapB[r][0][0]);
            wapB[r][0][1] = __builtin_elementwise_fma(t0, wp4, wapB[r][0][1]);
            wapB[r][1][0] = __builtin_elementwise_fma(t1, wp3, wapB[r][1][0]);
            wapB[r][1][1] = __builtin_elementwise_fma(t1, wp4, wapB[r][1][1]);
          }
        }
      }

      // ---- consume pass B: maxpool p6..9 ----
#pragma unroll
      for (int r = 0; r < NR; ++r) {
#pragma unroll
        for (int p = 6; p < PP; ++p) {
          int pi = (p >> 1) - 3;
          float a0 = (p & 1) ? wapB[r][0][pi].y : wapB[r][0][pi].x;
          float a1 = (p & 1) ? wapB[r][1][pi].y : wapB[r][1][pi].x;
          float v0 = a0 * N2WI[dird][j0][p];
          float v1 = act1 ? a1 * N2WI[dird][j1c][p] : -3.4e38f;
          float m = wave_max(fmaxf(v0, v1));
          if (lane == 0) {
            out[((i0 + r) * BBATCH + b) * OC + 20 + dird * PP + p] = m * N1WI[sl + r][p];
          }
        }
      }
    } // wapB dead here

    // ---- Phase D: mean-att accumulation, packed (d0,d1); reads own CROW rows ----
    for (int j = 0; j < TT; ++j) {
      v2f s2ab; s2ab.x = S2V[dird][c0i][j][k0]; s2ab.y = S2V[dird][c1i][j][k1];
#pragma unroll
      for (int r = 0; r < NR; ++r) {
        float cv = CROW[sl + r][j];
        v2f cc; cc.x = cv; cc.y = cv;
        attp[r] = __builtin_elementwise_fma(cc, s2ab, attp[r]);
      }
    }

    // overwrite own CROW rows with att rows (same-wave ordering suffices)
#pragma unroll
    for (int r = 0; r < NR; ++r) {
      float inv = 1.0f / (rs[r] + FEPS);
      CROW[sl + r][lane] = attp[r].x * inv;
      if (actd) CROW[sl + r][64 + lane] = attp[r].y * inv;
    }

    // ---- Phase E: epilogue: 60 tasks = 2 rows x {full, mean-att, att2} x 10 p
    if (lane < NR * 30) {
      int tk = lane;
      int r = tk / 30;
      int q = tk - r * 30;
      int set = q / PP;
      int p = q - set * PP;
      const float* wrow = (set == 0 ? wfull : (set == 1 ? wmean : watt2)) + p * DD;
      // reference quirk: s2.reshape(-1,D)[argmax] == s2f[0, argmax, :] (fwd only)
      const float* gat = s2 + ARGJ[sl + r] * (2 * DD);
      float num = 0.f, nx = 0.f, ny = 0.f;
      for (int c = 0; c < DC; ++c) {
        v4f x4 = *(const v4f*)&S1R[sl + r][4 * c];
        v4f y4;
        if (set == 0)                     y4 = *(const v4f*)&S2V[dird][c][TT - 1][0];
        else if (set == 1 || dird == 1)   y4 = *(const v4f*)&CROW[sl + r][4 * c];
        else                              y4 = *(const v4f*)&gat[4 * c];
        v4f w4 = *(const v4f*)&wrow[4 * c];
#pragma unroll
        for (int k = 0; k < 4; ++k) {
          float w2v = w4[k] * w4[k];
          num = fmaf(x4[k] * y4[k], w2v, num);
          nx  = fmaf(x4[k] * x4[k], w2v, nx);
          ny  = fmaf(y4[k] * y4[k], w2v, ny);
        }
      }
      float cres = num * rsqrtf(fmaxf(nx, FEPS)) * rsqrtf(fmaxf(ny, FEPS));
      int ch = (set == 0 ? 0 : (set == 1 ? 40 : 60)) + dird * PP + p;
      out[((i0 + r) * BBATCH + b) * OC + ch] = cres;
    }
  }
}

extern "C" void kernel_launch(void* const* d_in, const int* in_sizes, int n_in,
                              void* d_out, int out_size, void* d_ws, size_t ws_size,
                              hipStream_t stream) {
  const float* s1 = (const float*)d_in[0];
  const float* s2 = (const float*)d_in[1];
  match_kernel<<<dim3(BBATCH), dim3(1024), 0, stream>>>(
      s1, s2,
      (const float*)d_in[2], (const float*)d_in[3],
      (const float*)d_in[4], (const float*)d_in[5],
      (const float*)d_in[6], (const float*)d_in[7],
      (const float*)d_in[8], (const float*)d_in[9],
      (float*)d_out);
}